// Round 6
// baseline (47.346 us; speedup 1.0000x reference)
//
#include <hip/hip_runtime.h>

#define NQ 10
#define EMBED 1024

// ---------------------------------------------------------------------------
// Closed-form ev (validated R1-R5, passing at absmax 2e-3):
// conjugate circuit by H^10 -> RX gates become diagonal phases, CNOT ring
// becomes reversed ring sigma.  <Z_q> collapses to a trig polynomial:
//   ev_q = sum_{S subset u_q, T=sigma^T S subset v_q} i^(|T|+|S|)
//          prod_{T} sinA prod_{v\T} cosA * prod_{S} sinB prod_{u\S} cosB
// Odd-parity terms are imaginary and cancel -> filtered at constexpr time.
// ---------------------------------------------------------------------------

constexpr int kPop(int x) { int c = 0; for (int i = 0; i < 10; ++i) c += (x >> i) & 1; return c; }

constexpr int sigma_map(int a) {
    int b = 0;
    for (int i = 0; i < 9; ++i) b |= (((a >> i) & 1) ^ ((a >> (i + 1)) & 1)) << i;
    b |= (((a >> 9) & 1) ^ ((a >> 0) & 1) ^ ((a >> 1) & 1)) << 9;
    return b;
}

#define MAXT 40
struct Terms {
    int nt[NQ];
    int vm[NQ];
    int um[NQ];
    unsigned short tm[NQ][MAXT];
    unsigned short sm[NQ][MAXT];
    float sg[NQ][MAXT];
};

constexpr Terms gen_terms() {
    Terms t{};
    int inv_e[NQ] = {};
    for (int a = 0; a < 1024; ++a) {
        const int s = sigma_map(a);
        for (int q = 0; q < NQ; ++q) if (s == (1 << q)) inv_e[q] = a;
    }
    for (int q = 0; q < NQ; ++q) {
        const int u = inv_e[q];
        int v = 0;
        for (int w = 0; w < NQ; ++w) if ((u >> w) & 1) v ^= inv_e[w];
        t.um[q] = u; t.vm[q] = v;
        int n = 0;
        int S = 0;
        while (true) {
            int T = (((S >> 0) ^ (S >> 9)) & 1)
                  | ((((S >> 0) ^ (S >> 1) ^ (S >> 9)) & 1) << 1);
            for (int j = 2; j < 10; ++j) T |= ((((S >> (j - 1)) ^ (S >> j)) & 1) << j);
            if ((T & ~v) == 0) {
                const int p = kPop(T) + kPop(S);
                if (!(p & 1)) {
                    t.tm[q][n] = (unsigned short)T;
                    t.sm[q][n] = (unsigned short)S;
                    t.sg[q][n] = (p & 2) ? -1.f : 1.f;
                    ++n;
                }
            }
            if (S == u) break;
            S = (S - u) & u;
        }
        t.nt[q] = n;
    }
    return t;
}

constexpr Terms TT = gen_terms();

// ===========================================================================
// Kernel 1: ev per row, written into out[row*1024 + q] (first 10 floats of
// each output row used as scratch; K2 reads them before overwriting).
// 8 waves; wave handles 4 rows (G=32 lanes/row, 2 rows/lane). Single barrier.
// ===========================================================================
extern "C" __global__ __launch_bounds__(512, 4)
void ffq_ev_kernel(const float* __restrict__ x, const float* __restrict__ W1,
                   const float* __restrict__ b1, const float* __restrict__ qw,
                   float* __restrict__ out)
{
    __shared__ float sW1[NQ * EMBED];             // 40 KiB

    const int tid  = threadIdx.x;
    const int lane = tid & 63;
    const int wv   = tid >> 6;          // 0..7
    const int o    = lane & 31;         // k-slice lane within row
    const int g    = lane >> 5;         // group 0..1 (2 rows each)
    const int block0 = blockIdx.x * 32;

    // ---- stage W1 into LDS ----
    {
        const float4* src = (const float4*)W1;
        float4* dst = (float4*)sW1;
        #pragma unroll
        for (int i = 0; i < 5; ++i) dst[tid + 512 * i] = src[tid + 512 * i];
    }

    float b1r[NQ], qw0[NQ];
    #pragma unroll
    for (int w = 0; w < NQ; ++w) { qw0[w] = qw[w]; b1r[w] = b1[w]; }

    __syncthreads();

    // ---- dots: 4 rows/wave, 32 lanes/row, 2 rows/lane ----
    const int rloc0 = wv * 4 + g * 2;
    float acc0[NQ], acc1[NQ];
    #pragma unroll
    for (int q = 0; q < NQ; ++q) { acc0[q] = 0.f; acc1[q] = 0.f; }

    const float4* xr0 = (const float4*)(x + (size_t)(block0 + rloc0) * EMBED);
    const float4* xr1 = (const float4*)(x + (size_t)(block0 + rloc0 + 1) * EMBED);
    const float4* w1v = (const float4*)sW1;
    #pragma unroll
    for (int k = 0; k < 8; ++k) {
        const float4 xv0 = xr0[k * 32 + o];
        const float4 xv1 = xr1[k * 32 + o];
        #pragma unroll
        for (int q = 0; q < NQ; ++q) {
            const float4 wv4 = w1v[q * 256 + k * 32 + o];
            acc0[q] = fmaf(xv0.x, wv4.x, acc0[q]);
            acc0[q] = fmaf(xv0.y, wv4.y, acc0[q]);
            acc0[q] = fmaf(xv0.z, wv4.z, acc0[q]);
            acc0[q] = fmaf(xv0.w, wv4.w, acc0[q]);
            acc1[q] = fmaf(xv1.x, wv4.x, acc1[q]);
            acc1[q] = fmaf(xv1.y, wv4.y, acc1[q]);
            acc1[q] = fmaf(xv1.z, wv4.z, acc1[q]);
            acc1[q] = fmaf(xv1.w, wv4.w, acc1[q]);
        }
    }
    #pragma unroll
    for (int m = 1; m < 32; m <<= 1) {
        #pragma unroll
        for (int q = 0; q < NQ; ++q) {
            acc0[q] += __shfl_xor(acc0[q], m, 64);
            acc1[q] += __shfl_xor(acc1[q], m, 64);
        }
    }

    // ---- in-wave redistribute angles: lane -> (row r, q-set grp) ----
    // rows of this wave: wv*4 + r, r = lane&3; holder lane = (r&2)?32:0,
    // value in acc0 (r even) or acc1 (r odd).
    const int r   = lane & 3;
    const int grp = lane >> 2;          // 0..6 used (28 active lanes)
    const int srcl = (r & 2) ? 32 : 0;

    float ca[NQ], sa[NQ], cb[NQ], sb[NQ];
    #pragma unroll
    for (int w = 0; w < NQ; ++w) {
        const float a0 = __shfl(acc0[w], srcl, 64);
        const float a1 = __shfl(acc1[w], srcl, 64);
        const float A  = ((r & 1) ? a1 : a0) + b1r[w] + qw0[w];
        ca[w] = __cosf(A); sa[w] = __sinf(A);
        const float B = qw[NQ + w];
        cb[w] = __cosf(B); sb[w] = __sinf(B);
    }

    if (grp < 7) {
        float* orow = out + (size_t)(block0 + wv * 4 + r) * EMBED;
        #define EVQ(QC) do {                                                      \
            float ev = 0.f;                                                       \
            _Pragma("unroll")                                                     \
            for (int k = 0; k < TT.nt[QC]; ++k) {                                 \
                float P = TT.sg[QC][k];                                           \
                _Pragma("unroll")                                                 \
                for (int w = 0; w < NQ; ++w) {                                    \
                    if ((TT.vm[QC] >> w) & 1) P *= ((TT.tm[QC][k] >> w) & 1) ? sa[w] : ca[w]; \
                    if ((TT.um[QC] >> w) & 1) P *= ((TT.sm[QC][k] >> w) & 1) ? sb[w] : cb[w]; \
                }                                                                 \
                ev += P;                                                          \
            }                                                                     \
            orow[QC] = ev;                                                        \
        } while (0)
        switch (grp) {
            case 0: EVQ(0); break;
            case 1: EVQ(9); break;
            case 2: EVQ(7); break;
            case 3: EVQ(8); break;
            case 4: EVQ(5); EVQ(6); break;
            case 5: EVQ(3); EVQ(4); break;
            default: EVQ(1); EVQ(2); break;
        }
        #undef EVQ
    }
}

// ===========================================================================
// Kernel 2: out[r][e] = b2[e] + sum_q ev[r][q]*W2[e][q].  Pure write stream.
// ev read from out[r][0..9] (written by K1), staged to LDS behind a barrier
// so no store can precede the reads.
// ===========================================================================
extern "C" __global__ __launch_bounds__(256, 4)
void ffq_out_kernel(const float* __restrict__ W2, const float* __restrict__ b2,
                    float* __restrict__ out)
{
    __shared__ float sev[80];           // 8 rows x 10 q

    const int tid = threadIdx.x;
    const int r0  = blockIdx.x * 8;

    // W2/b2 for this thread's float4 column (issue first, hides latency)
    float w2f[40];
    {
        const float4* w2v = (const float4*)(W2 + tid * 40);
        #pragma unroll
        for (int i = 0; i < 10; ++i) {
            float4 v = w2v[i];
            w2f[4*i+0] = v.x; w2f[4*i+1] = v.y; w2f[4*i+2] = v.z; w2f[4*i+3] = v.w;
        }
    }
    const float4 b2v = ((const float4*)b2)[tid];

    if (tid < 80) {
        const int rr = tid / 10;
        const int qq = tid - rr * 10;
        sev[tid] = out[(size_t)(r0 + rr) * EMBED + qq];
    }
    __syncthreads();

    #pragma unroll
    for (int rr = 0; rr < 8; ++rr) {
        float o0 = b2v.x, o1 = b2v.y, o2 = b2v.z, o3 = b2v.w;
        #pragma unroll
        for (int q = 0; q < NQ; ++q) {
            const float e = sev[rr * 10 + q];
            o0 = fmaf(e, w2f[ 0 + q], o0);
            o1 = fmaf(e, w2f[10 + q], o1);
            o2 = fmaf(e, w2f[20 + q], o2);
            o3 = fmaf(e, w2f[30 + q], o3);
        }
        float4 ov = {o0, o1, o2, o3};
        ((float4*)(out + (size_t)(r0 + rr) * EMBED))[tid] = ov;
    }
}

extern "C" void kernel_launch(void* const* d_in, const int* in_sizes, int n_in,
                              void* d_out, int out_size, void* d_ws, size_t ws_size,
                              hipStream_t stream) {
    (void)in_sizes; (void)n_in; (void)d_ws; (void)ws_size; (void)out_size;
    const float* x  = (const float*)d_in[0];
    const float* W1 = (const float*)d_in[1];
    const float* b1 = (const float*)d_in[2];
    const float* qw = (const float*)d_in[3];
    const float* W2 = (const float*)d_in[4];
    const float* b2 = (const float*)d_in[5];
    float* out = (float*)d_out;

    ffq_ev_kernel<<<dim3(512), 512, 0, stream>>>(x, W1, b1, qw, out);
    ffq_out_kernel<<<dim3(2048), 256, 0, stream>>>(W2, b2, out);
}

// Round 7
// 36.001 us; speedup vs baseline: 1.3151x; 1.3151x over previous
//
#include <hip/hip_runtime.h>

#define NQ 10
#define EMBED 1024

// ---------------------------------------------------------------------------
// Closed-form ev (validated R1-R6, passing at absmax 2e-3):
// conjugate circuit by H^10 -> RX gates become diagonal phases, CNOT ring
// becomes reversed ring sigma.  <Z_q> collapses to a trig polynomial:
//   ev_q = sum_{S subset u_q, T=sigma^T S subset v_q} i^(|T|+|S|)
//          prod_{T} sinA prod_{v\T} cosA * prod_{S} sinB prod_{u\S} cosB
// Odd-parity terms are imaginary and cancel -> filtered at constexpr time.
// ---------------------------------------------------------------------------

constexpr int kPop(int x) { int c = 0; for (int i = 0; i < 10; ++i) c += (x >> i) & 1; return c; }

constexpr int sigma_map(int a) {
    int b = 0;
    for (int i = 0; i < 9; ++i) b |= (((a >> i) & 1) ^ ((a >> (i + 1)) & 1)) << i;
    b |= (((a >> 9) & 1) ^ ((a >> 0) & 1) ^ ((a >> 1) & 1)) << 9;
    return b;
}

#define MAXT 40
struct Terms {
    int nt[NQ];
    int vm[NQ];
    int um[NQ];
    unsigned short tm[NQ][MAXT];
    unsigned short sm[NQ][MAXT];
    float sg[NQ][MAXT];
};

constexpr Terms gen_terms() {
    Terms t{};
    int inv_e[NQ] = {};
    for (int a = 0; a < 1024; ++a) {
        const int s = sigma_map(a);
        for (int q = 0; q < NQ; ++q) if (s == (1 << q)) inv_e[q] = a;
    }
    for (int q = 0; q < NQ; ++q) {
        const int u = inv_e[q];
        int v = 0;
        for (int w = 0; w < NQ; ++w) if ((u >> w) & 1) v ^= inv_e[w];
        t.um[q] = u; t.vm[q] = v;
        int n = 0;
        int S = 0;
        while (true) {
            int T = (((S >> 0) ^ (S >> 9)) & 1)
                  | ((((S >> 0) ^ (S >> 1) ^ (S >> 9)) & 1) << 1);
            for (int j = 2; j < 10; ++j) T |= ((((S >> (j - 1)) ^ (S >> j)) & 1) << j);
            if ((T & ~v) == 0) {
                const int p = kPop(T) + kPop(S);
                if (!(p & 1)) {
                    t.tm[q][n] = (unsigned short)T;
                    t.sm[q][n] = (unsigned short)S;
                    t.sg[q][n] = (p & 2) ? -1.f : 1.f;
                    ++n;
                }
            }
            if (S == u) break;
            S = (S - u) & u;
        }
        t.nt[q] = n;
    }
    return t;
}

constexpr Terms TT = gen_terms();

// ---- DPP 32-lane sum: VALU-pipe reduction (no DS traffic) -----------------
// steps: xor1 (quad_perm 1,0,3,2), xor2 (quad_perm 2,3,0,1),
// row_half_mirror (pairs quads across 8), row_mirror (pairs 8s across 16),
// row_bcast15 into DPP-rows 1,3 only (row_mask 0xA): full 32-lane sums are
// valid in lanes 16..31 (group 0) and 48..63 (group 1).
template <int CTRL, int RM>
__device__ __forceinline__ float dppadd(float v) {
    const int s = __builtin_amdgcn_update_dpp(0, __float_as_int(v), CTRL, RM, 0xF, true);
    return v + __int_as_float(s);
}
__device__ __forceinline__ float red32(float v) {
    v = dppadd<0xB1,  0xF>(v);
    v = dppadd<0x4E,  0xF>(v);
    v = dppadd<0x141, 0xF>(v);
    v = dppadd<0x140, 0xF>(v);
    v = dppadd<0x142, 0xA>(v);
    return v;
}

// ===========================================================================
// Kernel 1: angles + closed-form ev, written into out[row*1024 + q] as
// scratch (K2 reads before overwriting).  8 waves; wave covers 4 rows
// (2 groups x 32 lanes, 2 rows per lane).  One barrier.
// ===========================================================================
extern "C" __global__ __launch_bounds__(512, 4)
void ffq_ev_kernel(const float* __restrict__ x, const float* __restrict__ W1,
                   const float* __restrict__ b1, const float* __restrict__ qw,
                   float* __restrict__ out)
{
    __shared__ float sW1[NQ * EMBED];             // 40 KiB
    __shared__ float sCA[32][NQ];
    __shared__ float sSA[32][NQ];

    const int tid  = threadIdx.x;
    const int lane = tid & 63;
    const int wv   = tid >> 6;          // 0..7
    const int o31  = lane & 31;         // k-slice lane within row
    const int g    = lane >> 5;         // group 0..1 (2 rows each)
    const int block0 = blockIdx.x * 32;

    // ---- stage W1 into LDS ----
    {
        const float4* src = (const float4*)W1;
        float4* dst = (float4*)sW1;
        #pragma unroll
        for (int i = 0; i < 5; ++i) dst[tid + 512 * i] = src[tid + 512 * i];
    }

    float b1r[NQ], qw0[NQ];
    #pragma unroll
    for (int w = 0; w < NQ; ++w) { qw0[w] = qw[w]; b1r[w] = b1[w]; }

    __syncthreads();

    // ---- dots: 4 rows/wave, 32 lanes/row, 2 rows/lane, x double-buffered --
    const int rloc0 = wv * 4 + g * 2;
    float acc0[NQ], acc1[NQ];
    #pragma unroll
    for (int q = 0; q < NQ; ++q) { acc0[q] = 0.f; acc1[q] = 0.f; }

    const float4* xr0 = (const float4*)(x + (size_t)(block0 + rloc0) * EMBED);
    const float4* xr1 = (const float4*)(x + (size_t)(block0 + rloc0 + 1) * EMBED);
    const float4* w1v = (const float4*)sW1;

    float4 nx0 = xr0[o31];
    float4 nx1 = xr1[o31];
    #pragma unroll
    for (int k = 0; k < 8; ++k) {
        const float4 xv0 = nx0;
        const float4 xv1 = nx1;
        if (k < 7) {
            nx0 = xr0[(k + 1) * 32 + o31];
            nx1 = xr1[(k + 1) * 32 + o31];
        }
        #pragma unroll
        for (int q = 0; q < NQ; ++q) {
            const float4 wv4 = w1v[q * 256 + k * 32 + o31];   // broadcast x2 groups
            acc0[q] = fmaf(xv0.x, wv4.x, acc0[q]);
            acc0[q] = fmaf(xv0.y, wv4.y, acc0[q]);
            acc0[q] = fmaf(xv0.z, wv4.z, acc0[q]);
            acc0[q] = fmaf(xv0.w, wv4.w, acc0[q]);
            acc1[q] = fmaf(xv1.x, wv4.x, acc1[q]);
            acc1[q] = fmaf(xv1.y, wv4.y, acc1[q]);
            acc1[q] = fmaf(xv1.z, wv4.z, acc1[q]);
            acc1[q] = fmaf(xv1.w, wv4.w, acc1[q]);
        }
    }

    // ---- DPP reduction over the 32 lanes of each group (VALU pipe) ----
    #pragma unroll
    for (int q = 0; q < NQ; ++q) {
        acc0[q] = red32(acc0[q]);
        acc1[q] = red32(acc1[q]);
    }

    // ---- writer lanes (o31==16 -> row rloc0, o31==17 -> row rloc0+1) ----
    if (o31 == 16) {
        #pragma unroll
        for (int w = 0; w < NQ; ++w) {
            const float A = acc0[w] + b1r[w] + qw0[w];
            sCA[rloc0][w] = __cosf(A);
            sSA[rloc0][w] = __sinf(A);
        }
    } else if (o31 == 17) {
        #pragma unroll
        for (int w = 0; w < NQ; ++w) {
            const float A = acc1[w] + b1r[w] + qw0[w];
            sCA[rloc0 + 1][w] = __cosf(A);
            sSA[rloc0 + 1][w] = __sinf(A);
        }
    }

    __syncthreads();

    // ---- ev: wave-uniform q-set per wave, lane = row (lanes 0..31) ----
    if (lane < 32) {
        const int row = lane;
        float ca[NQ], sa[NQ], cb[NQ], sb[NQ];
        #pragma unroll
        for (int w = 0; w < NQ; ++w) {
            ca[w] = sCA[row][w];
            sa[w] = sSA[row][w];
            const float B = qw[NQ + w];
            cb[w] = __cosf(B); sb[w] = __sinf(B);
        }
        float* orow = out + (size_t)(block0 + row) * EMBED;
        #define EVQ(QC) do {                                                      \
            float ev = 0.f;                                                       \
            _Pragma("unroll")                                                     \
            for (int k = 0; k < TT.nt[QC]; ++k) {                                 \
                float P = TT.sg[QC][k];                                           \
                _Pragma("unroll")                                                 \
                for (int w = 0; w < NQ; ++w) {                                    \
                    if ((TT.vm[QC] >> w) & 1) P *= ((TT.tm[QC][k] >> w) & 1) ? sa[w] : ca[w]; \
                    if ((TT.um[QC] >> w) & 1) P *= ((TT.sm[QC][k] >> w) & 1) ? sb[w] : cb[w]; \
                }                                                                 \
                ev += P;                                                          \
            }                                                                     \
            orow[QC] = ev;                                                        \
        } while (0)
        switch (wv) {
            case 0: EVQ(0); break;
            case 1: EVQ(9); break;
            case 2: EVQ(7); break;
            case 3: EVQ(8); break;
            case 4: EVQ(5); EVQ(6); break;
            case 5: EVQ(3); EVQ(4); break;
            case 6: EVQ(1); EVQ(2); break;
            default: break;              // wave 7 idle
        }
        #undef EVQ
    }
}

// ===========================================================================
// Kernel 2: out[r][e] = b2[e] + sum_q ev[r][q]*W2[e][q].  Pure write stream.
// ev read from out[r][0..9] (written by K1), staged to LDS behind a barrier
// so no store can precede the reads.
// ===========================================================================
extern "C" __global__ __launch_bounds__(256, 4)
void ffq_out_kernel(const float* __restrict__ W2, const float* __restrict__ b2,
                    float* __restrict__ out)
{
    __shared__ float sev[80];           // 8 rows x 10 q

    const int tid = threadIdx.x;
    const int r0  = blockIdx.x * 8;

    float w2f[40];
    {
        const float4* w2v = (const float4*)(W2 + tid * 40);
        #pragma unroll
        for (int i = 0; i < 10; ++i) {
            float4 v = w2v[i];
            w2f[4*i+0] = v.x; w2f[4*i+1] = v.y; w2f[4*i+2] = v.z; w2f[4*i+3] = v.w;
        }
    }
    const float4 b2v = ((const float4*)b2)[tid];

    if (tid < 80) {
        const int rr = tid / 10;
        const int qq = tid - rr * 10;
        sev[tid] = out[(size_t)(r0 + rr) * EMBED + qq];
    }
    __syncthreads();

    #pragma unroll
    for (int rr = 0; rr < 8; ++rr) {
        float o0 = b2v.x, o1 = b2v.y, o2 = b2v.z, o3 = b2v.w;
        #pragma unroll
        for (int q = 0; q < NQ; ++q) {
            const float e = sev[rr * 10 + q];
            o0 = fmaf(e, w2f[ 0 + q], o0);
            o1 = fmaf(e, w2f[10 + q], o1);
            o2 = fmaf(e, w2f[20 + q], o2);
            o3 = fmaf(e, w2f[30 + q], o3);
        }
        float4 ov = {o0, o1, o2, o3};
        ((float4*)(out + (size_t)(r0 + rr) * EMBED))[tid] = ov;
    }
}

extern "C" void kernel_launch(void* const* d_in, const int* in_sizes, int n_in,
                              void* d_out, int out_size, void* d_ws, size_t ws_size,
                              hipStream_t stream) {
    (void)in_sizes; (void)n_in; (void)d_ws; (void)ws_size; (void)out_size;
    const float* x  = (const float*)d_in[0];
    const float* W1 = (const float*)d_in[1];
    const float* b1 = (const float*)d_in[2];
    const float* qw = (const float*)d_in[3];
    const float* W2 = (const float*)d_in[4];
    const float* b2 = (const float*)d_in[5];
    float* out = (float*)d_out;

    ffq_ev_kernel<<<dim3(512), 512, 0, stream>>>(x, W1, b1, qw, out);
    ffq_out_kernel<<<dim3(2048), 256, 0, stream>>>(W2, b2, out);
}